// Round 7
// baseline (92.853 us; speedup 1.0000x reference)
//
#include <hip/hip_runtime.h>
#include <hip/hip_bf16.h>

#define DIM 1024
#define SEQ 4096
#define NB 4
#define MROWS (NB * SEQ)   // 16384
#define NC 64              // chunks per sequence
#define CL (SEQ / NC)      // 64 L-positions per chunk

// GEMM tiling: 256x256 tile, BK=64 (2 ksteps of 32), 2 LDS slots, 8 waves 2Mx4N
#define BM 256
#define BN 256
#define NTILE 16                 // K-tiles of 64: 1024/64
#define NITER 8                  // main-loop iterations (2 K-tiles each)
#define SLOT_BYTES 65536         // A(32KB: ks0,ks1) + B(32KB)
#define GEMM_LDS (2 * SLOT_BYTES)  // 128 KiB

typedef __attribute__((ext_vector_type(8))) short bf16x8;
typedef __attribute__((ext_vector_type(4))) float f32x4;

static __device__ __forceinline__ unsigned short f2bf(float f) {
    union { float f; unsigned u; } v; v.f = f;
    unsigned r = v.u + 0x7FFF + ((v.u >> 16) & 1);
    return (unsigned short)(r >> 16);
}

static __device__ __forceinline__ float bf2f(unsigned short h) {
    union { unsigned u; float f; } v; v.u = ((unsigned)h) << 16;
    return v.f;
}

static __device__ __forceinline__ void gload_lds16(const void* g, void* l) {
    __builtin_amdgcn_global_load_lds((const __attribute__((address_space(1))) void*)g,
                                     (__attribute__((address_space(3))) void*)l, 16, 0, 0);
}

// ---- convert x and W fp32 -> bf16 (into d_out scratch) ----
__global__ void convert_kernel(const float* __restrict__ x, const float* __restrict__ W,
                               unsigned short* __restrict__ xb, unsigned short* __restrict__ wb) {
    const long long NX4 = (long long)MROWS * DIM / 4;
    const long long NW4 = (long long)DIM * DIM / 4;
    long long t = (long long)blockIdx.x * blockDim.x + threadIdx.x;
    if (t < NX4) {
        float4 v = ((const float4*)x)[t];
        ushort4 o;
        o.x = f2bf(v.x); o.y = f2bf(v.y); o.z = f2bf(v.z); o.w = f2bf(v.w);
        ((ushort4*)xb)[t] = o;
    } else if (t < NX4 + NW4) {
        long long u = t - NX4;
        float4 v = ((const float4*)W)[u];
        ushort4 o;
        o.x = f2bf(v.x); o.y = f2bf(v.y); o.z = f2bf(v.z); o.w = f2bf(v.w);
        ((ushort4*)wb)[u] = o;
    }
}

// Stage one half-tile (256 rows x 32 cols bf16 = 16KB) of K-tile `tile`,
// ks-half `ks`, operand `ab` (0=A,1=B) into LDS slot tile&1.
// LDS rows are 64B with 16B slots XOR-permuted: slot s holds global chunk
// s ^ ((row>>1)&3) (involution; undone by swz on ds_read). Zero-conflict
// verified round 4 (SQ_LDS_BANK_CONFLICT = 0).
static __device__ __forceinline__ void stage_ht(const unsigned short* __restrict__ src, char* smem,
                                                int r0, int tile, int ks, int ab, int tid) {
    const int sc16 = (tid & 3) ^ ((tid >> 3) & 3);
    char* dst = smem + (size_t)(tile & 1) * SLOT_BYTES + ab * 32768 + ks * 16384
              + (tid >> 2) * 64 + (tid & 3) * 16;
    const unsigned short* g = src + (size_t)(r0 + (tid >> 2)) * DIM
                            + (tile & (NTILE - 1)) * 64 + ks * 32 + sc16 * 8;
    gload_lds16(g, dst);                       // rows 0..127
    gload_lds16(g + (size_t)128 * DIM, dst + 128 * 64);  // rows 128..255
}

// One of the 8 phases: {frag ds_reads + 1 half-tile stage -> [vmcnt(8)] ->
// barrier -> lgkmcnt(0) -> setprio(1) 16 MFMA setprio(0) -> barrier}
template<int MFB, bool LOADB, bool VM>
static __device__ __forceinline__ void do_phase(const char* sbase, int ks,
    const unsigned short* __restrict__ ssrc, char* smem, int sr0, int stile, int sks, int sab,
    int tid, int wr, int wc, int rl, int swz, f32x4 acc[8][4], bf16x8 bfr[4])
{
    bf16x8 af[4];
    if (LOADB) {
#pragma unroll
        for (int nf = 0; nf < 4; ++nf)
            bfr[nf] = *(const bf16x8*)(sbase + 32768 + ks * 16384 + (wc + nf * 16 + rl) * 64 + swz);
    }
#pragma unroll
    for (int mf = 0; mf < 4; ++mf)
        af[mf] = *(const bf16x8*)(sbase + ks * 16384 + (wr + (MFB + mf) * 16 + rl) * 64 + swz);
    stage_ht(ssrc, smem, sr0, stile, sks, sab, tid);
    if (VM) asm volatile("s_waitcnt vmcnt(8)" ::: "memory");
    __builtin_amdgcn_sched_barrier(0);
    __builtin_amdgcn_s_barrier();
    asm volatile("s_waitcnt lgkmcnt(0)" ::: "memory");
    __builtin_amdgcn_sched_barrier(0);
    __builtin_amdgcn_s_setprio(1);
#pragma unroll
    for (int mf = 0; mf < 4; ++mf)
#pragma unroll
        for (int nf = 0; nf < 4; ++nf)
            acc[MFB + mf][nf] = __builtin_amdgcn_mfma_f32_16x16x32_bf16(af[mf], bfr[nf], acc[MFB + mf][nf], 0, 0, 0);
    __builtin_amdgcn_s_setprio(0);
    __builtin_amdgcn_sched_barrier(0);
    __builtin_amdgcn_s_barrier();
}

// ---- GEMM: V[m][n] = bf16( sum_k A[m][k]*B[n][k] + bias[n] ) ----
// 8-phase counted-vmcnt schedule (m201 port). Iter i computes K-tiles 2i (slot0,
// phases 1-4) and 2i+1 (slot1, phases 5-8); stages per phase:
//   p1: A-ks1(2i+1)  p2: B-ks1(2i+1)+vm  p3: A-ks0(2i+2)  p4: B-ks0(2i+2)+vm
//   p5: A-ks1(2i+2)  p6: B-ks1(2i+2)+vm  p7: A-ks0(2i+3)  p8: B-ks0(2i+3)+vm
// Every stage writes a region whose reads finished >=1 barrier earlier; every
// vmcnt(8) drains exactly the half-tile pair needed 1 phase later (5-phase slack).
__global__ __launch_bounds__(512, 2) void gemm_kernel(const unsigned short* __restrict__ A,
                                                      const unsigned short* __restrict__ Bm,
                                                      const float* __restrict__ bias,
                                                      unsigned short* __restrict__ V) {
    extern __shared__ char smem[];
    const int tid  = threadIdx.x;
    const int lane = tid & 63;
    const int w    = tid >> 6;           // wave 0..7
    const int wr   = (w >> 2) * 128;     // wave row offset (M)
    const int wc   = (w & 3) * 64;       // wave col offset (N)
    const int rl   = lane & 15;
    const int rh   = lane >> 4;
    const int swz  = (rh ^ ((rl >> 1) & 3)) * 16;
    const int m0   = blockIdx.x * BM;
    const int n0   = blockIdx.y * BN;
    const char* s0 = smem;               // slot0 (even tiles)
    const char* s1 = smem + SLOT_BYTES;  // slot1 (odd tiles)

    f32x4 acc[8][4];
#pragma unroll
    for (int m = 0; m < 8; ++m)
#pragma unroll
        for (int n = 0; n < 4; ++n)
            acc[m][n] = (f32x4){0.f, 0.f, 0.f, 0.f};

    float bv[4];
#pragma unroll
    for (int nf = 0; nf < 4; ++nf)
        bv[nf] = bias[n0 + wc + nf * 16 + rl];

    // prologue: ks0(0), ks1(0), ks0(1) = 6 half-tiles (12 loads/thread)
    stage_ht(A,  smem, m0, 0, 0, 0, tid);
    stage_ht(Bm, smem, n0, 0, 0, 1, tid);
    stage_ht(A,  smem, m0, 0, 1, 0, tid);
    stage_ht(Bm, smem, n0, 0, 1, 1, tid);
    stage_ht(A,  smem, m0, 1, 0, 0, tid);
    stage_ht(Bm, smem, n0, 1, 0, 1, tid);
    asm volatile("s_waitcnt vmcnt(8)" ::: "memory");   // ks0(0) resident
    __builtin_amdgcn_s_barrier();

    bf16x8 bfr[4];
#pragma unroll 1
    for (int i = 0; i < NITER; ++i) {
        const int t1 = 2 * i + 1, t2 = 2 * i + 2, t3 = 2 * i + 3;  // &15 inside stage
        do_phase<0, true,  false>(s0, 0, A,  smem, m0, t1, 1, 0, tid, wr, wc, rl, swz, acc, bfr); // p1
        do_phase<4, false, true >(s0, 0, Bm, smem, n0, t1, 1, 1, tid, wr, wc, rl, swz, acc, bfr); // p2
        do_phase<0, true,  false>(s0, 1, A,  smem, m0, t2, 0, 0, tid, wr, wc, rl, swz, acc, bfr); // p3
        do_phase<4, false, true >(s0, 1, Bm, smem, n0, t2, 0, 1, tid, wr, wc, rl, swz, acc, bfr); // p4
        do_phase<0, true,  false>(s1, 0, A,  smem, m0, t2, 1, 0, tid, wr, wc, rl, swz, acc, bfr); // p5
        do_phase<4, false, true >(s1, 0, Bm, smem, n0, t2, 1, 1, tid, wr, wc, rl, swz, acc, bfr); // p6
        do_phase<0, true,  false>(s1, 1, A,  smem, m0, t3, 0, 0, tid, wr, wc, rl, swz, acc, bfr); // p7
        do_phase<4, false, true >(s1, 1, Bm, smem, n0, t3, 0, 1, tid, wr, wc, rl, swz, acc, bfr); // p8
    }

    // epilogue: C/D layout col = lane&15, row = (lane>>4)*4 + reg; store bf16
#pragma unroll
    for (int mf = 0; mf < 8; ++mf) {
#pragma unroll
        for (int nf = 0; nf < 4; ++nf) {
            int gcol = n0 + wc + nf * 16 + rl;
#pragma unroll
            for (int j = 0; j < 4; ++j) {
                int grow = m0 + wr + mf * 16 + rh * 4 + j;
                V[(size_t)grow * DIM + gcol] = f2bf(acc[mf][nf][j] + bv[nf]);
            }
        }
    }
}

// ---- pass A: per-chunk sums of v*cos, v*sin. 2 e-columns/thread ----
__global__ void passA_kernel(const unsigned short* __restrict__ val, const float* __restrict__ ph,
                             float* __restrict__ pr, float* __restrict__ pi) {
    int t  = blockIdx.x * 256 + threadIdx.x;
    int c  = blockIdx.y;
    int bb = blockIdx.z;
    const ushort2* v = (const ushort2*)val + ((size_t)bb * SEQ + (size_t)c * CL) * (DIM / 2) + t;
    const float2*  p = (const float2*)ph + (size_t)c * CL * (DIM / 2) + t;
    float sr0 = 0.f, si0 = 0.f, sr1 = 0.f, si1 = 0.f;
    for (int l = 0; l < CL; ++l) {
        ushort2 vv = v[(size_t)l * (DIM / 2)];
        float2  pp = p[(size_t)l * (DIM / 2)];
        float v0 = bf2f(vv.x), v1 = bf2f(vv.y);
        float s0, c0, s1, c1;
        __sincosf(pp.x, &s0, &c0);
        __sincosf(pp.y, &s1, &c1);
        sr0 += v0 * c0; si0 += v0 * s0;
        sr1 += v1 * c1; si1 += v1 * s1;
    }
    size_t idx = ((size_t)bb * NC + c) * DIM + 2 * t;
    pr[idx] = sr0; pr[idx + 1] = sr1;
    pi[idx] = si0; pi[idx + 1] = si1;
}

// ---- pass B: exclusive scan of chunk partials over c ----
__global__ void passB_kernel(float* __restrict__ pr, float* __restrict__ pi) {
    int t = blockIdx.x * 256 + threadIdx.x;
    int bb = t >> 10;
    int e  = t & 1023;
    float r = 0.f, im = 0.f;
    for (int c = 0; c < NC; ++c) {
        size_t idx = ((size_t)bb * NC + c) * DIM + e;
        float tr = pr[idx], ti = pi[idx];
        pr[idx] = r; pi[idx] = im;
        r += tr; im += ti;
    }
}

// ---- pass C: running cumsum + retrieval + norm -> fp32 out ----
__global__ void passC_kernel(const unsigned short* __restrict__ val, const float* __restrict__ ph,
                             const float* __restrict__ pr, const float* __restrict__ pi,
                             float* __restrict__ out) {
    int t  = blockIdx.x * 256 + threadIdx.x;
    int c  = blockIdx.y;
    int bb = blockIdx.z;
    size_t base = ((size_t)bb * SEQ + (size_t)c * CL) * (DIM / 2) + t;
    const ushort2* v = (const ushort2*)val + base;
    const float2*  p = (const float2*)ph + (size_t)c * CL * (DIM / 2) + t;
    float2* o = (float2*)out + base;
    size_t pidx = ((size_t)bb * NC + c) * DIM + 2 * t;
    float ar0 = pr[pidx], ar1 = pr[pidx + 1];
    float ai0 = pi[pidx], ai1 = pi[pidx + 1];
    const int l0 = c * CL;
    for (int l = 0; l < CL; ++l) {
        ushort2 vv = v[(size_t)l * (DIM / 2)];
        float2  pp = p[(size_t)l * (DIM / 2)];
        float v0 = bf2f(vv.x), v1 = bf2f(vv.y);
        float s0, c0, s1, c1;
        __sincosf(pp.x, &s0, &c0);
        __sincosf(pp.y, &s1, &c1);
        ar0 += v0 * c0; ai0 += v0 * s0;
        ar1 += v1 * c1; ai1 += v1 * s1;
        float rn = rsqrtf((float)(l0 + l + 1));
        float2 ov;
        ov.x = (ar0 * c0 + ai0 * s0) * rn;
        ov.y = (ar1 * c1 + ai1 * s1) * rn;
        o[(size_t)l * (DIM / 2)] = ov;
    }
}

extern "C" void kernel_launch(void* const* d_in, const int* in_sizes, int n_in,
                              void* d_out, int out_size, void* d_ws, size_t ws_size,
                              hipStream_t stream) {
    const float* x  = (const float*)d_in[0];
    const float* ph = (const float*)d_in[1];
    const float* W  = (const float*)d_in[2];
    const float* b  = (const float*)d_in[3];
    float* out = (float*)d_out;

    // d_out doubles as scratch for bf16 inputs until passC overwrites it
    unsigned short* xb = (unsigned short*)d_out;
    unsigned short* wb = xb + (size_t)MROWS * DIM;

    // ws: vb bf16 32MB | pr 256KB | pi 256KB
    unsigned short* vb = (unsigned short*)d_ws;
    float* pr = (float*)(vb + (size_t)MROWS * DIM);
    float* pi = pr + (size_t)NB * NC * DIM;

    (void)hipFuncSetAttribute((const void*)gemm_kernel,
                              hipFuncAttributeMaxDynamicSharedMemorySize, GEMM_LDS);

    // 1) convert x, W to bf16 (into d_out scratch region)
    {
        long long total4 = (long long)MROWS * DIM / 4 + (long long)DIM * DIM / 4;
        int blocks = (int)((total4 + 255) / 256);
        convert_kernel<<<blocks, 256, 0, stream>>>(x, W, xb, wb);
    }
    // 2) GEMM -> bf16 value into ws
    {
        dim3 grid(MROWS / BM, DIM / BN);
        gemm_kernel<<<grid, 512, GEMM_LDS, stream>>>(xb, wb, b, vb);
    }
    // 3) chunk partial sums
    {
        dim3 grid(DIM / 512, NC, NB);
        passA_kernel<<<grid, 256, 0, stream>>>(vb, ph, pr, pi);
    }
    // 4) scan partials
    passB_kernel<<<16, 256, 0, stream>>>(pr, pi);
    // 5) final cumsum + retrieve + norm -> fp32 d_out
    {
        dim3 grid(DIM / 512, NC, NB);
        passC_kernel<<<grid, 256, 0, stream>>>(vb, ph, pr, pi, out);
    }
}

// Round 8
// 88.588 us; speedup vs baseline: 1.0481x; 1.0481x over previous
//
#include <hip/hip_runtime.h>
#include <hip/hip_bf16.h>

#define DIM 1024
#define SEQ 4096
#define NB 4
#define MROWS (NB * SEQ)   // 16384
#define NC 64              // chunks per sequence
#define CL (SEQ / NC)      // 64 L-positions per chunk

// GEMM tiling: 256x256 tile, BK=32, 3 LDS slots (A fp32 32KB + B bf16 16KB each)
#define BM 256
#define BN 256
#define BK 32
#define NTK 32                   // K-tiles: 1024/32
#define SLOTB 49152              // 48 KB per slot
#define GEMM_LDS (3 * SLOTB)     // 144 KB

typedef __attribute__((ext_vector_type(8))) short bf16x8;
typedef __attribute__((ext_vector_type(4))) float f32x4;

static __device__ __forceinline__ unsigned short f2bf(float f) {
    union { float f; unsigned u; } v; v.f = f;
    unsigned r = v.u + 0x7FFF + ((v.u >> 16) & 1);
    return (unsigned short)(r >> 16);
}

static __device__ __forceinline__ float bf2f(unsigned short h) {
    union { unsigned u; float f; } v; v.u = ((unsigned)h) << 16;
    return v.f;
}

// v_cvt_pk_bf16_f32: RNE, lo=bf16(a) in bits[15:0], hi=bf16(b) in bits[31:16]
static __device__ __forceinline__ unsigned cvtpk(float a, float b) {
    unsigned r;
    asm("v_cvt_pk_bf16_f32 %0, %1, %2" : "=v"(r) : "v"(a), "v"(b));
    return r;
}

static __device__ __forceinline__ void gload_lds16(const void* g, void* l) {
    __builtin_amdgcn_global_load_lds((const __attribute__((address_space(1))) void*)g,
                                     (__attribute__((address_space(3))) void*)l, 16, 0, 0);
}

// ---- convert W fp32 -> bf16 (tiny) ----
__global__ void convertW_kernel(const float* __restrict__ W, unsigned short* __restrict__ wb) {
    int t = blockIdx.x * 256 + threadIdx.x;
    float4 v = ((const float4*)W)[t];
    ushort4 o;
    o.x = f2bf(v.x); o.y = f2bf(v.y); o.z = f2bf(v.z); o.w = f2bf(v.w);
    ((ushort4*)wb)[t] = o;
}

// Stage A K-tile (256 rows x 32 cols fp32 = 32 KB) of tile kt into slot.
// LDS rows 128B = 8 chunks of 16B, stored slot s holds global chunk s^(row&7).
// Wave w, load j covers rows (w*4+j)*8 .. +7 : dst = base + lane*16 (linear, 1KB/wave-load);
// src chunk = (lane&7) ^ (lane>>3)  [row&7 == lane>>3 for this mapping].
static __device__ __forceinline__ void stage_Af32(const float* __restrict__ srcBase, char* smem,
                                                  int slot, int kt, int w, int lane) {
#pragma unroll
    for (int j = 0; j < 4; ++j) {
        const float* g = srcBase + (size_t)j * 8 * DIM + kt * BK;
        char* l = smem + (size_t)slot * SLOTB + (w * 4 + j) * 1024 + lane * 16;
        gload_lds16(g, l);
    }
}

// Stage B K-tile (256 rows x 32 cols bf16 = 16 KB) into slot at offset 32KB.
// LDS rows 64B = 4 chunks; stored slot s holds chunk s^((row>>1)&3) (verified
// zero-conflict in round 4).
static __device__ __forceinline__ void stage_B16(const unsigned short* __restrict__ srcBase, char* smem,
                                                 int slot, int kt, int w, int lane) {
#pragma unroll
    for (int r = 0; r < 2; ++r) {
        const unsigned short* g = srcBase + (size_t)r * 128 * DIM + kt * BK;
        char* l = smem + (size_t)slot * SLOTB + 32768 + (r * 128 + w * 16) * 64 + lane * 16;
        gload_lds16(g, l);
    }
}

// ---- GEMM: V[m][n] = bf16( sum_k X[m][k]*W[n][k] + bias[n] ) ----
// A staged as fp32 (x-conversion fused via cvt_pk after ds_read); B staged bf16.
// 3-slot rotation, 2-ahead staging, counted vmcnt(6) (never drains in loop).
// MFMA operands SWAPPED (bfr first) so lane's 4 acc regs = 4 consecutive output
// columns -> coalesced ushort4 C-store.
__global__ __launch_bounds__(512, 2) void gemm_kernel(const float* __restrict__ X,
                                                      const unsigned short* __restrict__ Bm,
                                                      const float* __restrict__ bias,
                                                      unsigned short* __restrict__ V) {
    extern __shared__ char smem[];
    const int tid  = threadIdx.x;
    const int lane = tid & 63;
    const int w    = tid >> 6;           // wave 0..7
    const int wr   = (w >> 2) * 128;     // wave row offset (M)
    const int wc   = (w & 3) * 64;       // wave col offset (N)
    const int rl   = lane & 15;
    const int rh   = lane >> 4;
    const int m0   = blockIdx.x * BM;
    const int n0   = blockIdx.y * BN;

    // per-thread staging source bases (chunk XOR folded in; per-lane global src is fine)
    const float* srcA = X + (size_t)(m0 + w * 32 + (lane >> 3)) * DIM + ((lane & 7) ^ (lane >> 3)) * 4;
    const unsigned short* srcB = Bm + (size_t)(n0 + w * 16 + (lane >> 2)) * DIM
                               + (((lane & 3) ^ ((lane >> 3) & 3)) * 8);

    // read-side offsets
    const int swzB = (rh ^ ((rl >> 1) & 3)) * 16;                       // B: undo 4-chunk XOR
    const int aoff0 = (wr + rl) * 128 + (((rh * 2 + 0) ^ (rl & 7)) * 16); // A sub0
    const int aoff1 = (wr + rl) * 128 + (((rh * 2 + 1) ^ (rl & 7)) * 16); // A sub1

    f32x4 acc[8][4];
#pragma unroll
    for (int m = 0; m < 8; ++m)
#pragma unroll
        for (int n = 0; n < 4; ++n)
            acc[m][n] = (f32x4){0.f, 0.f, 0.f, 0.f};

    float4 bv4[4];
#pragma unroll
    for (int nf = 0; nf < 4; ++nf)
        bv4[nf] = *(const float4*)(bias + n0 + wc + nf * 16 + rh * 4);

    // prologue: stage tiles 0 (slot0) and 1 (slot1); 12 loads/thread
    stage_Af32(srcA, smem, 0, 0, w, lane);
    stage_B16 (srcB, smem, 0, 0, w, lane);
    stage_Af32(srcA, smem, 1, 1, w, lane);
    stage_B16 (srcB, smem, 1, 1, w, lane);

#pragma unroll 1
    for (int t = 0; t < NTK; ++t) {
        // tile t resident: drain all but the 6 newest loads (tile t+1's)
        asm volatile("s_waitcnt vmcnt(6)" ::: "memory");
        __builtin_amdgcn_s_barrier();
        const int sc = t % 3;
        const int ss = (t + 2) % 3;
        const int kn = (t + 2) & (NTK - 1);   // tail wraps into dead slots (safe)
        const char* sb = smem + (size_t)sc * SLOTB;

        // B fragments (bf16 direct)
        bf16x8 bfr[4];
#pragma unroll
        for (int nf = 0; nf < 4; ++nf)
            bfr[nf] = *(const bf16x8*)(sb + 32768 + (wc + nf * 16 + rl) * 64 + swzB);

        // A fragments mf 0..3 : fp32 ds_read + cvt_pk
        bf16x8 af[4];
#pragma unroll
        for (int mf = 0; mf < 4; ++mf) {
            f32x4 q0 = *(const f32x4*)(sb + mf * 2048 + aoff0);
            f32x4 q1 = *(const f32x4*)(sb + mf * 2048 + aoff1);
            union { unsigned u[4]; bf16x8 v; } cv;
            cv.u[0] = cvtpk(q0[0], q0[1]); cv.u[1] = cvtpk(q0[2], q0[3]);
            cv.u[2] = cvtpk(q1[0], q1[1]); cv.u[3] = cvtpk(q1[2], q1[3]);
            af[mf] = cv.v;
        }
        stage_Af32(srcA, smem, ss, kn, w, lane);
        __builtin_amdgcn_s_setprio(1);
#pragma unroll
        for (int mf = 0; mf < 4; ++mf)
#pragma unroll
            for (int nf = 0; nf < 4; ++nf)
                acc[mf][nf] = __builtin_amdgcn_mfma_f32_16x16x32_bf16(bfr[nf], af[mf], acc[mf][nf], 0, 0, 0);
        __builtin_amdgcn_s_setprio(0);

        // A fragments mf 4..7
#pragma unroll
        for (int mf = 0; mf < 4; ++mf) {
            f32x4 q0 = *(const f32x4*)(sb + (mf + 4) * 2048 + aoff0);
            f32x4 q1 = *(const f32x4*)(sb + (mf + 4) * 2048 + aoff1);
            union { unsigned u[4]; bf16x8 v; } cv;
            cv.u[0] = cvtpk(q0[0], q0[1]); cv.u[1] = cvtpk(q0[2], q0[3]);
            cv.u[2] = cvtpk(q1[0], q1[1]); cv.u[3] = cvtpk(q1[2], q1[3]);
            af[mf] = cv.v;
        }
        stage_B16(srcB, smem, ss, kn, w, lane);
        __builtin_amdgcn_s_setprio(1);
#pragma unroll
        for (int mf = 0; mf < 4; ++mf)
#pragma unroll
            for (int nf = 0; nf < 4; ++nf)
                acc[mf + 4][nf] = __builtin_amdgcn_mfma_f32_16x16x32_bf16(bfr[nf], af[mf], acc[mf + 4][nf], 0, 0, 0);
        __builtin_amdgcn_s_setprio(0);
    }

    // epilogue: swapped-operand C/D layout -> lane holds row m = wr+mf*16+rl,
    // cols n = wc+nf*16+rh*4+j (j contiguous) -> coalesced ushort4 stores
#pragma unroll
    for (int mf = 0; mf < 8; ++mf) {
        int grow = m0 + wr + mf * 16 + rl;
#pragma unroll
        for (int nf = 0; nf < 4; ++nf) {
            int gcol0 = n0 + wc + nf * 16 + rh * 4;
            ushort4 o;
            o.x = f2bf(acc[mf][nf][0] + bv4[nf].x);
            o.y = f2bf(acc[mf][nf][1] + bv4[nf].y);
            o.z = f2bf(acc[mf][nf][2] + bv4[nf].z);
            o.w = f2bf(acc[mf][nf][3] + bv4[nf].w);
            *(ushort4*)(V + (size_t)grow * DIM + gcol0) = o;
        }
    }
}

// ---- pass A: per-chunk sums of v*cos, v*sin. 2 e-columns/thread ----
__global__ void passA_kernel(const unsigned short* __restrict__ val, const float* __restrict__ ph,
                             float* __restrict__ pr, float* __restrict__ pi) {
    int t  = blockIdx.x * 256 + threadIdx.x;
    int c  = blockIdx.y;
    int bb = blockIdx.z;
    const ushort2* v = (const ushort2*)val + ((size_t)bb * SEQ + (size_t)c * CL) * (DIM / 2) + t;
    const float2*  p = (const float2*)ph + (size_t)c * CL * (DIM / 2) + t;
    float sr0 = 0.f, si0 = 0.f, sr1 = 0.f, si1 = 0.f;
    for (int l = 0; l < CL; ++l) {
        ushort2 vv = v[(size_t)l * (DIM / 2)];
        float2  pp = p[(size_t)l * (DIM / 2)];
        float v0 = bf2f(vv.x), v1 = bf2f(vv.y);
        float s0, c0, s1, c1;
        __sincosf(pp.x, &s0, &c0);
        __sincosf(pp.y, &s1, &c1);
        sr0 += v0 * c0; si0 += v0 * s0;
        sr1 += v1 * c1; si1 += v1 * s1;
    }
    size_t idx = ((size_t)bb * NC + c) * DIM + 2 * t;
    pr[idx] = sr0; pr[idx + 1] = sr1;
    pi[idx] = si0; pi[idx + 1] = si1;
}

// ---- pass B: exclusive scan of chunk partials over c ----
__global__ void passB_kernel(float* __restrict__ pr, float* __restrict__ pi) {
    int t = blockIdx.x * 256 + threadIdx.x;
    int bb = t >> 10;
    int e  = t & 1023;
    float r = 0.f, im = 0.f;
    for (int c = 0; c < NC; ++c) {
        size_t idx = ((size_t)bb * NC + c) * DIM + e;
        float tr = pr[idx], ti = pi[idx];
        pr[idx] = r; pi[idx] = im;
        r += tr; im += ti;
    }
}

// ---- pass C: running cumsum + retrieval + norm -> fp32 out ----
__global__ void passC_kernel(const unsigned short* __restrict__ val, const float* __restrict__ ph,
                             const float* __restrict__ pr, const float* __restrict__ pi,
                             float* __restrict__ out) {
    int t  = blockIdx.x * 256 + threadIdx.x;
    int c  = blockIdx.y;
    int bb = blockIdx.z;
    size_t base = ((size_t)bb * SEQ + (size_t)c * CL) * (DIM / 2) + t;
    const ushort2* v = (const ushort2*)val + base;
    const float2*  p = (const float2*)ph + (size_t)c * CL * (DIM / 2) + t;
    float2* o = (float2*)out + base;
    size_t pidx = ((size_t)bb * NC + c) * DIM + 2 * t;
    float ar0 = pr[pidx], ar1 = pr[pidx + 1];
    float ai0 = pi[pidx], ai1 = pi[pidx + 1];
    const int l0 = c * CL;
    for (int l = 0; l < CL; ++l) {
        ushort2 vv = v[(size_t)l * (DIM / 2)];
        float2  pp = p[(size_t)l * (DIM / 2)];
        float v0 = bf2f(vv.x), v1 = bf2f(vv.y);
        float s0, c0, s1, c1;
        __sincosf(pp.x, &s0, &c0);
        __sincosf(pp.y, &s1, &c1);
        ar0 += v0 * c0; ai0 += v0 * s0;
        ar1 += v1 * c1; ai1 += v1 * s1;
        float rn = rsqrtf((float)(l0 + l + 1));
        float2 ov;
        ov.x = (ar0 * c0 + ai0 * s0) * rn;
        ov.y = (ar1 * c1 + ai1 * s1) * rn;
        o[(size_t)l * (DIM / 2)] = ov;
    }
}

extern "C" void kernel_launch(void* const* d_in, const int* in_sizes, int n_in,
                              void* d_out, int out_size, void* d_ws, size_t ws_size,
                              hipStream_t stream) {
    const float* x  = (const float*)d_in[0];
    const float* ph = (const float*)d_in[1];
    const float* W  = (const float*)d_in[2];
    const float* b  = (const float*)d_in[3];
    float* out = (float*)d_out;

    // ws: vb bf16 32MB | wb 2MB | pr 256KB | pi 256KB
    unsigned short* vb = (unsigned short*)d_ws;
    unsigned short* wb = vb + (size_t)MROWS * DIM;
    float* pr = (float*)(wb + (size_t)DIM * DIM);
    float* pi = pr + (size_t)NB * NC * DIM;

    (void)hipFuncSetAttribute((const void*)gemm_kernel,
                              hipFuncAttributeMaxDynamicSharedMemorySize, GEMM_LDS);

    // 1) convert W only (x-conversion fused into GEMM LDS pipeline)
    convertW_kernel<<<DIM * DIM / 4 / 256, 256, 0, stream>>>(W, wb);
    // 2) GEMM (reads fp32 x directly) -> bf16 value into ws
    {
        dim3 grid(MROWS / BM, DIM / BN);
        gemm_kernel<<<grid, 512, GEMM_LDS, stream>>>(x, wb, b, vb);
    }
    // 3) chunk partial sums
    {
        dim3 grid(DIM / 512, NC, NB);
        passA_kernel<<<grid, 256, 0, stream>>>(vb, ph, pr, pi);
    }
    // 4) scan partials
    passB_kernel<<<16, 256, 0, stream>>>(pr, pi);
    // 5) final cumsum + retrieve + norm -> fp32 d_out
    {
        dim3 grid(DIM / 512, NC, NB);
        passC_kernel<<<grid, 256, 0, stream>>>(vb, ph, pr, pi, out);
    }
}